// Round 1
// baseline (265.793 us; speedup 1.0000x reference)
//
#include <hip/hip_runtime.h>
#include <stdint.h>

typedef __bf16 bf16x8_t __attribute__((ext_vector_type(8)));
typedef float f32x4_t __attribute__((ext_vector_type(4)));

__device__ __forceinline__ uint32_t f32_to_bf16_bits(float f) {
    union { float f; uint32_t u; } v; v.f = f;
    return (v.u + 0x7FFFu + ((v.u >> 16) & 1u)) >> 16;   // RNE, finite inputs
}

// ---------------------------------------------------------------------------
// Merged prep (unchanged):
//  blocks [0,4096):    Ae[n,r]=cos(pi*2r(2n+1)/8192), Ao[n,r]=cos(pi*(2r+1)(2n+1)/8192)
//  blocks [4096,12288): Xe[q,r]=bf16(x[q,2r]), Xo[q,r]=bf16(x[q,2r+1])
// ---------------------------------------------------------------------------
__global__ void prep_kernel(const float* __restrict__ X,
                            unsigned short* __restrict__ Ae,
                            unsigned short* __restrict__ Ao,
                            unsigned short* __restrict__ Xe,
                            unsigned short* __restrict__ Xo) {
    if (blockIdx.x < 4096) {
        const int idx = blockIdx.x * 256 + threadIdx.x;   // 0..1M-1
        const int sel = idx >> 19;                        // 0=even, 1=odd matrix
        const int e   = idx & ((1 << 19) - 1);
        const int n   = e >> 8;                           // 0..2047
        const int c0  = (e & 255) << 3;                   // col start
        const uint32_t tn = (uint32_t)(2 * n + 1);
        unsigned short* dst = sel ? Ao : Ae;
        uint32_t packed[4];
#pragma unroll
        for (int jj = 0; jj < 4; ++jj) {
            uint32_t cA = (uint32_t)(c0 + 2 * jj);
            uint32_t cB = cA + 1;
            uint32_t r0 = ((2u * cA + (uint32_t)sel) * tn) & 16383u;
            uint32_t r1 = ((2u * cB + (uint32_t)sel) * tn) & 16383u;
            float v0 = __cosf((float)r0 * 3.8349519697141e-4f);   // pi/8192
            float v1 = __cosf((float)r1 * 3.8349519697141e-4f);
            packed[jj] = f32_to_bf16_bits(v0) | (f32_to_bf16_bits(v1) << 16);
        }
        *(uint4*)(dst + (size_t)n * 2048 + c0) = make_uint4(packed[0], packed[1], packed[2], packed[3]);
    } else {
        const int idx = (blockIdx.x - 4096) * 256 + threadIdx.x;   // 0..2M-1
        const int q   = idx >> 9;
        const int p0  = (idx & 511) << 3;
        const float4* src = (const float4*)(X + (size_t)q * 4096 + p0);
        float4 a = src[0];
        float4 b = src[1];
        uint2 ev, od;
        ev.x = f32_to_bf16_bits(a.x) | (f32_to_bf16_bits(a.z) << 16);
        ev.y = f32_to_bf16_bits(b.x) | (f32_to_bf16_bits(b.z) << 16);
        od.x = f32_to_bf16_bits(a.y) | (f32_to_bf16_bits(a.w) << 16);
        od.y = f32_to_bf16_bits(b.y) | (f32_to_bf16_bits(b.w) << 16);
        *(uint2*)(Xe + (size_t)q * 2048 + (p0 >> 1)) = ev;
        *(uint2*)(Xo + (size_t)q * 2048 + (p0 >> 1)) = od;
    }
}

// ---------------------------------------------------------------------------
// Phased dual-parity GEMM + butterfly epilogue.
//
// 128(cos-dim) x 256(data-dim) tile, BK=64, 512 threads = 8 waves (2Mx4N),
// per-wave 64x64 per parity, mfma_f32_16x16x32_bf16.
// Virtual K = 4096: tiles 0..31 = parity-e (acc_e), 32..63 = parity-o (acc_o).
//
// 3-deep LDS buffering (3 x [A 128x64 | B 256x64] bf16 = 144 KB) with
// counted-vmcnt pipeline: tile t's compute overlaps tile t+1 (landed-checking
// via vmcnt(6)) and tile t+2 (loads being issued). vmcnt never drains to 0 in
// steady state. Raw s_barrier (NOT __syncthreads -> no forced vmcnt(0) drain).
//
// LDS chunk swizzle (unchanged from prior kernel): phys slot s of row r holds
// logical k-chunk g = s ^ (r&7); staging pre-swizzles the *global* source
// address (global_load_lds dest must stay linear), reads XOR on the slot.
// ---------------------------------------------------------------------------
#define GLL(gp, lp) __builtin_amdgcn_global_load_lds( \
        (const __attribute__((address_space(1))) uint32_t*)(gp), \
        (__attribute__((address_space(3))) uint32_t*)(lp), 16, 0, 0)

template <bool PRE, int VM>
__device__ __forceinline__ void tile_step(f32x4_t (&acc)[4][4], const int t,
        int& cur_off, int& stg_off, unsigned short* smem,
        const unsigned short* pAe, const unsigned short* pAo,
        const unsigned short* pBe, const unsigned short* pBo,
        const int* a_src, const int* b_src, const int* a_lds, const int* b_lds,
        const int aRow, const int bRow, const int gq, const int sw) {
    const unsigned short* gA = pAe;
    const unsigned short* gB = pBe;
    size_t kadv = 0;
    if (PRE) {
        const int pre = t + 2;                      // virtual tile to prefetch
        gA = (pre < 32) ? pAe : pAo;
        gB = (pre < 32) ? pBe : pBo;
        kadv = (size_t)(pre & 31) << 6;             // *64 shorts
    }
    unsigned short* sA = smem + stg_off;            // prefetch target (buf t+2)
    unsigned short* sB = sA + 8192;
    const unsigned short* lA = smem + cur_off;      // compute source (buf t)
    const unsigned short* lB = lA + 8192;

#pragma unroll
    for (int kh = 0; kh < 2; ++kh) {                // 2 phases per K-tile
        const int so = (((kh << 2) + gq) ^ sw) << 3;
        bf16x8_t af[4], bfr[4];
#pragma unroll
        for (int i = 0; i < 4; ++i) af[i]  = *(const bf16x8_t*)(lA + aRow + i * 1024 + so);
#pragma unroll
        for (int j = 0; j < 4; ++j) bfr[j] = *(const bf16x8_t*)(lB + bRow + j * 1024 + so);
        if (PRE) {
            if (kh == 0) {
                GLL(gA + kadv + a_src[0], sA + a_lds[0]);
                GLL(gB + kadv + b_src[0], sB + b_lds[0]);
                GLL(gB + kadv + b_src[1], sB + b_lds[1]);
            } else {
                GLL(gA + kadv + a_src[1], sA + a_lds[1]);
                GLL(gB + kadv + b_src[2], sB + b_lds[2]);
                GLL(gB + kadv + b_src[3], sB + b_lds[3]);
            }
        }
        asm volatile("" ::: "memory");
        __builtin_amdgcn_s_barrier();
        __builtin_amdgcn_s_setprio(1);
#pragma unroll
        for (int i = 0; i < 4; ++i)
#pragma unroll
            for (int j = 0; j < 4; ++j)
                acc[i][j] = __builtin_amdgcn_mfma_f32_16x16x32_bf16(af[i], bfr[j], acc[i][j], 0, 0, 0);
        __builtin_amdgcn_s_setprio(0);
        if (kh == 1) {
            // once per K-tile: ensure tile t+1 fully landed; t+2's 6 loads stay in flight
            if (VM == 6)      asm volatile("s_waitcnt vmcnt(6)" ::: "memory");
            else if (VM == 0) asm volatile("s_waitcnt vmcnt(0)" ::: "memory");
        }
        asm volatile("" ::: "memory");
        __builtin_amdgcn_s_barrier();
    }
    cur_off += 24576; if (cur_off == 73728) cur_off = 0;
    stg_off += 24576; if (stg_off == 73728) stg_off = 0;
}

template <int STAGE>
__global__ __launch_bounds__(512, 2)
void gemm_fused_kernel(const unsigned short* __restrict__ Ae,
                       const unsigned short* __restrict__ Ao,
                       const unsigned short* __restrict__ Re,
                       const unsigned short* __restrict__ Ro,
                       unsigned short* __restrict__ Te,
                       unsigned short* __restrict__ To,
                       float* __restrict__ out) {
    constexpr int KD = 2048;
    // 3 buffers x (A 8192 + B 16384 shorts) = 73728 shorts = 144 KB
    __shared__ __attribute__((aligned(16))) unsigned short smem[3 * 24576];

    const int tid  = threadIdx.x;
    const int wave = tid >> 6;
    const int lane = tid & 63;
    const int wm   = wave >> 2;     // 0..1 (M: cosine dim)
    const int wn   = wave & 3;      // 0..3 (N: data dim)

    const int tile_n = blockIdx.y << 7;   // cosine rows: [0,2048)
    const int tile_c = blockIdx.x << 8;   // data rows (= C cols): [0,4096)

    const unsigned short* pAe = Ae + (size_t)tile_n * KD;
    const unsigned short* pAo = Ao + (size_t)tile_n * KD;
    const unsigned short* pBe = Re + (size_t)tile_c * KD;
    const unsigned short* pBo = Ro + (size_t)tile_c * KD;

    f32x4_t acc_e[4][4], acc_o[4][4];
#pragma unroll
    for (int i = 0; i < 4; ++i)
#pragma unroll
        for (int j = 0; j < 4; ++j) {
            acc_e[i][j] = (f32x4_t){0.f, 0.f, 0.f, 0.f};
            acc_o[i][j] = (f32x4_t){0.f, 0.f, 0.f, 0.f};
        }

    // Staging: A-tile 1024 chunks of 16B (thread gets c=tid, tid+512);
    //          B-tile 2048 chunks (c = tid + 512*k, k<4).
    // Phys chunk c -> row c>>3, slot c&7; global source k-chunk g = slot ^ (row&7).
    int a_src[2], a_lds[2], b_src[4], b_lds[4];
#pragma unroll
    for (int k2 = 0; k2 < 2; ++k2) {
        const int c = tid + 512 * k2, row = c >> 3, g = (c & 7) ^ (row & 7);
        a_src[k2] = row * KD + g * 8;
        a_lds[k2] = c * 8;
    }
#pragma unroll
    for (int k2 = 0; k2 < 4; ++k2) {
        const int c = tid + 512 * k2, row = c >> 3, g = (c & 7) ^ (row & 7);
        b_src[k2] = row * KD + g * 8;
        b_lds[k2] = c * 8;
    }

    // Fragment read addressing (swizzled).
    const int frow = lane & 15;
    const int sw   = frow & 7;
    const int gq   = lane >> 4;
    const int aRow = (wm * 64 + frow) * 64;
    const int bRow = (wn * 64 + frow) * 64;

    // Prologue: stage tiles 0 (buf0) and 1 (buf1), both parity-e; keep tile1's
    // 6 loads in flight across the first barrier.
    {
        unsigned short* s0 = smem;
        GLL(pAe + a_src[0], s0 + a_lds[0]);
        GLL(pBe + b_src[0], s0 + 8192 + b_lds[0]);
        GLL(pBe + b_src[1], s0 + 8192 + b_lds[1]);
        GLL(pAe + a_src[1], s0 + a_lds[1]);
        GLL(pBe + b_src[2], s0 + 8192 + b_lds[2]);
        GLL(pBe + b_src[3], s0 + 8192 + b_lds[3]);
        unsigned short* s1 = smem + 24576;
        GLL(pAe + 64 + a_src[0], s1 + a_lds[0]);
        GLL(pBe + 64 + b_src[0], s1 + 8192 + b_lds[0]);
        GLL(pBe + 64 + b_src[1], s1 + 8192 + b_lds[1]);
        GLL(pAe + 64 + a_src[1], s1 + a_lds[1]);
        GLL(pBe + 64 + b_src[2], s1 + 8192 + b_lds[2]);
        GLL(pBe + 64 + b_src[3], s1 + 8192 + b_lds[3]);
        asm volatile("s_waitcnt vmcnt(6)" ::: "memory");
        __builtin_amdgcn_s_barrier();
    }

    int cur_off = 0;
    int stg_off = 49152;   // first prefetch targets virtual tile 2 -> buf2

#pragma unroll 1
    for (int t = 0; t < 32; ++t)
        tile_step<true, 6>(acc_e, t, cur_off, stg_off, smem, pAe, pAo, pBe, pBo,
                           a_src, b_src, a_lds, b_lds, aRow, bRow, gq, sw);
#pragma unroll 1
    for (int t = 32; t < 62; ++t)
        tile_step<true, 6>(acc_o, t, cur_off, stg_off, smem, pAe, pAo, pBe, pBo,
                           a_src, b_src, a_lds, b_lds, aRow, bRow, gq, sw);
    tile_step<false, 0>(acc_o, 62, cur_off, stg_off, smem, pAe, pAo, pBe, pBo,
                        a_src, b_src, a_lds, b_lds, aRow, bRow, gq, sw);
    tile_step<false, -1>(acc_o, 63, cur_off, stg_off, smem, pAe, pAo, pBe, pBo,
                         a_src, b_src, a_lds, b_lds, aRow, bRow, gq, sw);

    // C/D map: col = lane&15 (B/data dim), row = (lane>>4)*4 + reg (A/cos dim)
    const int orow0 = tile_n + wm * 64 + ((lane >> 4) << 2);
    const int ocol0 = tile_c + wn * 64 + (lane & 15);
    if (STAGE == 1) {
        unsigned short* dst = (ocol0 & 1) ? To : Te;   // parity fixed per thread
#pragma unroll
        for (int i = 0; i < 4; ++i)
#pragma unroll
            for (int j = 0; j < 4; ++j)
#pragma unroll
                for (int r = 0; r < 4; ++r) {
                    const int n = orow0 + i * 16 + r;
                    const int c = (ocol0 + j * 16) >> 1;
                    const float e = acc_e[i][j][r], o = acc_o[i][j][r];
                    dst[(size_t)n * 2048 + c]          = (unsigned short)f32_to_bf16_bits(e + o);
                    dst[(size_t)(4095 - n) * 2048 + c] = (unsigned short)f32_to_bf16_bits(e - o);
                }
    } else {
#pragma unroll
        for (int i = 0; i < 4; ++i)
#pragma unroll
            for (int j = 0; j < 4; ++j)
#pragma unroll
                for (int r = 0; r < 4; ++r) {
                    const int m = orow0 + i * 16 + r;
                    const int w = ocol0 + j * 16;
                    const float e = acc_e[i][j][r], o = acc_o[i][j][r];
                    out[(size_t)m * 4096 + w]          = e + o;
                    out[(size_t)(4095 - m) * 4096 + w] = e - o;
                }
    }
}

// ---------------------------------------------------------------------------
// Pipeline:
//   prep:   Ae,Ao (cosine tables) + Xe,Xo (deinterleaved bf16 x)
//   stage1: (Ae,Ao) x (Xe,Xo) -> butterfly -> Te,To (bf16, deinterleaved)
//   stage2: (Ae,Ao) x (Te,To) -> butterfly -> out (fp32)
// ws: Ae[0,8M) Ao[8,16M) Xe[16,32M) Xo[32,48M) Te[48,64M) To[64,80M)
// ---------------------------------------------------------------------------
extern "C" void kernel_launch(void* const* d_in, const int* in_sizes, int n_in,
                              void* d_out, int out_size, void* d_ws, size_t ws_size,
                              hipStream_t stream) {
    const float* x = (const float*)d_in[0];
    char* ws = (char*)d_ws;
    const size_t MB = 1024 * 1024;
    unsigned short* Ae = (unsigned short*)(ws);
    unsigned short* Ao = (unsigned short*)(ws + 8 * MB);
    unsigned short* Xe = (unsigned short*)(ws + 16 * MB);
    unsigned short* Xo = (unsigned short*)(ws + 32 * MB);
    unsigned short* Te = (unsigned short*)(ws + 48 * MB);
    unsigned short* To = (unsigned short*)(ws + 64 * MB);
    float* out = (float*)d_out;

    prep_kernel<<<12288, 256, 0, stream>>>(x, Ae, Ao, Xe, Xo);

    dim3 grid(16, 16);
    gemm_fused_kernel<1><<<grid, 512, 0, stream>>>(Ae, Ao, Xe, Xo, Te, To, nullptr);
    gemm_fused_kernel<2><<<grid, 512, 0, stream>>>(Ae, Ao, Te, To, nullptr, nullptr, out);
}

// Round 2
// 252.582 us; speedup vs baseline: 1.0523x; 1.0523x over previous
//
#include <hip/hip_runtime.h>
#include <stdint.h>

typedef __bf16 bf16x8_t __attribute__((ext_vector_type(8)));
typedef float f32x4_t __attribute__((ext_vector_type(4)));

__device__ __forceinline__ uint32_t f32_to_bf16_bits(float f) {
    union { float f; uint32_t u; } v; v.f = f;
    return (v.u + 0x7FFFu + ((v.u >> 16) & 1u)) >> 16;   // RNE, finite inputs
}

// ---------------------------------------------------------------------------
// Merged prep (unchanged):
//  blocks [0,4096):    Ae[n,r]=cos(pi*2r(2n+1)/8192), Ao[n,r]=cos(pi*(2r+1)(2n+1)/8192)
//  blocks [4096,12288): Xe[q,r]=bf16(x[q,2r]), Xo[q,r]=bf16(x[q,2r+1])
// ---------------------------------------------------------------------------
__global__ void prep_kernel(const float* __restrict__ X,
                            unsigned short* __restrict__ Ae,
                            unsigned short* __restrict__ Ao,
                            unsigned short* __restrict__ Xe,
                            unsigned short* __restrict__ Xo) {
    if (blockIdx.x < 4096) {
        const int idx = blockIdx.x * 256 + threadIdx.x;   // 0..1M-1
        const int sel = idx >> 19;                        // 0=even, 1=odd matrix
        const int e   = idx & ((1 << 19) - 1);
        const int n   = e >> 8;                           // 0..2047
        const int c0  = (e & 255) << 3;                   // col start
        const uint32_t tn = (uint32_t)(2 * n + 1);
        unsigned short* dst = sel ? Ao : Ae;
        uint32_t packed[4];
#pragma unroll
        for (int jj = 0; jj < 4; ++jj) {
            uint32_t cA = (uint32_t)(c0 + 2 * jj);
            uint32_t cB = cA + 1;
            uint32_t r0 = ((2u * cA + (uint32_t)sel) * tn) & 16383u;
            uint32_t r1 = ((2u * cB + (uint32_t)sel) * tn) & 16383u;
            float v0 = __cosf((float)r0 * 3.8349519697141e-4f);   // pi/8192
            float v1 = __cosf((float)r1 * 3.8349519697141e-4f);
            packed[jj] = f32_to_bf16_bits(v0) | (f32_to_bf16_bits(v1) << 16);
        }
        *(uint4*)(dst + (size_t)n * 2048 + c0) = make_uint4(packed[0], packed[1], packed[2], packed[3]);
    } else {
        const int idx = (blockIdx.x - 4096) * 256 + threadIdx.x;   // 0..2M-1
        const int q   = idx >> 9;
        const int p0  = (idx & 511) << 3;
        const float4* src = (const float4*)(X + (size_t)q * 4096 + p0);
        float4 a = src[0];
        float4 b = src[1];
        uint2 ev, od;
        ev.x = f32_to_bf16_bits(a.x) | (f32_to_bf16_bits(a.z) << 16);
        ev.y = f32_to_bf16_bits(b.x) | (f32_to_bf16_bits(b.z) << 16);
        od.x = f32_to_bf16_bits(a.y) | (f32_to_bf16_bits(a.w) << 16);
        od.y = f32_to_bf16_bits(b.y) | (f32_to_bf16_bits(b.w) << 16);
        *(uint2*)(Xe + (size_t)q * 2048 + (p0 >> 1)) = ev;
        *(uint2*)(Xo + (size_t)q * 2048 + (p0 >> 1)) = od;
    }
}

// ---------------------------------------------------------------------------
// Dual-parity GEMM + butterfly, minimum-2-phase pipeline (T3 recipe):
//
//   prologue: STAGE(tile0, buf0); vmcnt(0); barrier
//   loop:     STAGE(tile t+1, buf^1)   <- issued FIRST (overlaps compute)
//             ds_read + MFMA on buf    <- waves free-run, no mid barriers
//             vmcnt(0); s_barrier      <- ONE sync point per tile; drain is
//                                         cheap (MFMA covered the latency)
//
// 128x128 tile, 256 threads = 4 waves (2Mx2N), per-wave 64x64.
// Virtual K = 4096: tiles 0..31 = parity-e (acc_e), 32..63 = parity-o (acc_o),
// so each K-step stages only ONE parity pair: 2 x 32 KB double buffer = 64 KB
// -> 2 blocks/CU co-resident (implicit cross-block overlap preserved).
//
// LDS chunk swizzle (verified): phys slot s of row r holds logical k-chunk
// g = s ^ (r&7); staging pre-swizzles the *global* source address
// (global_load_lds dest must stay linear per-wave), reads XOR on the slot.
// ---------------------------------------------------------------------------
#define GLL(gp, lp) __builtin_amdgcn_global_load_lds( \
        (const __attribute__((address_space(1))) uint32_t*)(gp), \
        (__attribute__((address_space(3))) uint32_t*)(lp), 16, 0, 0)

// 8 GLL per thread: 4 A-chunks + 4 B-chunks. LDS dest base is wave-uniform
// (HW scatters lane*16B); global source carries the per-lane swizzled offset.
#define STAGE8(buf, gA, gB, kadv) do {                                        \
    _Pragma("unroll")                                                         \
    for (int k_ = 0; k_ < 4; ++k_) {                                          \
        GLL((gA) + (kadv) + src_off[k_], (buf) + uldsb[k_]);                  \
        GLL((gB) + (kadv) + src_off[k_], (buf) + 8192 + uldsb[k_]);           \
    }                                                                         \
} while (0)

#define COMPUTE_TILE(buf, acc) do {                                           \
    const unsigned short* lA_ = (buf);                                        \
    const unsigned short* lB_ = (buf) + 8192;                                 \
    _Pragma("unroll")                                                         \
    for (int kh_ = 0; kh_ < 2; ++kh_) {                                       \
        const int so_ = (((kh_ << 2) + gq) ^ sw) << 3;                        \
        bf16x8_t af_[4], bf_[4];                                              \
        _Pragma("unroll")                                                     \
        for (int i_ = 0; i_ < 4; ++i_) af_[i_] = *(const bf16x8_t*)(lA_ + aRow + i_ * 1024 + so_); \
        _Pragma("unroll")                                                     \
        for (int j_ = 0; j_ < 4; ++j_) bf_[j_] = *(const bf16x8_t*)(lB_ + bRow + j_ * 1024 + so_); \
        __builtin_amdgcn_s_setprio(1);                                        \
        _Pragma("unroll")                                                     \
        for (int i_ = 0; i_ < 4; ++i_)                                        \
            _Pragma("unroll")                                                 \
            for (int j_ = 0; j_ < 4; ++j_)                                    \
                acc[i_][j_] = __builtin_amdgcn_mfma_f32_16x16x32_bf16(af_[i_], bf_[j_], acc[i_][j_], 0, 0, 0); \
        __builtin_amdgcn_s_setprio(0);                                        \
    }                                                                         \
} while (0)

#define TILE_SYNC() do {                                                      \
    asm volatile("s_waitcnt vmcnt(0)" ::: "memory");                          \
    __builtin_amdgcn_s_barrier();                                             \
    asm volatile("" ::: "memory");                                            \
} while (0)

template <int STAGE>
__global__ __launch_bounds__(256, 2)
void gemm_fused_kernel(const unsigned short* __restrict__ Ae,
                       const unsigned short* __restrict__ Ao,
                       const unsigned short* __restrict__ Re,
                       const unsigned short* __restrict__ Ro,
                       unsigned short* __restrict__ Te,
                       unsigned short* __restrict__ To,
                       float* __restrict__ out) {
    constexpr int KD = 2048;
    // 2 buffers x (A 128x64 + B 128x64) bf16 = 2 x 16384 shorts = 64 KB
    __shared__ __attribute__((aligned(16))) unsigned short smem[2 * 16384];

    const int tid  = threadIdx.x;
    const int wave = tid >> 6;
    const int lane = tid & 63;

    const int tile_m = blockIdx.y << 7;   // cosine rows: [0,2048)
    const int tile_c = blockIdx.x << 7;   // data rows (= C cols): [0,4096)

    const unsigned short* pAe = Ae + (size_t)tile_m * KD;
    const unsigned short* pAo = Ao + (size_t)tile_m * KD;
    const unsigned short* pBe = Re + (size_t)tile_c * KD;
    const unsigned short* pBo = Ro + (size_t)tile_c * KD;

    f32x4_t acc_e[4][4], acc_o[4][4];
#pragma unroll
    for (int i = 0; i < 4; ++i)
#pragma unroll
        for (int j = 0; j < 4; ++j) {
            acc_e[i][j] = (f32x4_t){0.f, 0.f, 0.f, 0.f};
            acc_o[i][j] = (f32x4_t){0.f, 0.f, 0.f, 0.f};
        }

    // Staging geometry: per buffer half (A or B): 1024 chunks of 16B over
    // 128 rows x 8 slots. Wave w covers chunks c = w*64 + lane + 256*k.
    //   per-lane global src (swizzled): row = c>>3, g = (c&7)^(row&7)
    //   wave-uniform LDS base: (w*64 + 256*k) chunks
    int src_off[4], uldsb[4];
#pragma unroll
    for (int k = 0; k < 4; ++k) {
        const int c   = (wave << 6) + lane + (k << 8);
        const int row = c >> 3;
        const int g   = (c & 7) ^ (row & 7);
        src_off[k] = row * KD + (g << 3);
        uldsb[k]   = ((wave << 6) + (k << 8)) << 3;   // shorts
    }

    // Fragment read addressing (swizzled).
    const int frow = lane & 15;
    const int sw   = frow & 7;
    const int gq   = lane >> 4;
    const int aRow = ((wave >> 1) * 64 + frow) * 64;
    const int bRow = ((wave & 1) * 64 + frow) * 64;

    // Prologue: stage tile 0 (parity e) into buf0.
    STAGE8(smem, pAe, pBe, 0);
    TILE_SYNC();

    int co = 0;   // current compute buffer offset (shorts); staging uses co^16384
#pragma unroll 1
    for (int t = 0; t < 31; ++t) {
        STAGE8(smem + (co ^ 16384), pAe, pBe, (size_t)(t + 1) << 6);
        COMPUTE_TILE(smem + co, acc_e);
        TILE_SYNC();
        co ^= 16384;
    }
    // Transition: prefetch first parity-o tile while computing last parity-e.
    STAGE8(smem + (co ^ 16384), pAo, pBo, 0);
    COMPUTE_TILE(smem + co, acc_e);
    TILE_SYNC();
    co ^= 16384;
#pragma unroll 1
    for (int t = 0; t < 31; ++t) {
        STAGE8(smem + (co ^ 16384), pAo, pBo, (size_t)(t + 1) << 6);
        COMPUTE_TILE(smem + co, acc_o);
        TILE_SYNC();
        co ^= 16384;
    }
    COMPUTE_TILE(smem + co, acc_o);   // last tile: nothing left to stage

    // C/D map: col = lane&15 (B/data dim), row = (lane>>4)*4 + reg (A/cos dim)
    const int orow = tile_m + (wave >> 1) * 64 + ((lane >> 4) << 2);
    const int ocol = tile_c + (wave & 1) * 64 + (lane & 15);
    if (STAGE == 1) {
        unsigned short* dst = (ocol & 1) ? To : Te;   // parity fixed per thread
#pragma unroll
        for (int i = 0; i < 4; ++i)
#pragma unroll
            for (int j = 0; j < 4; ++j)
#pragma unroll
                for (int r = 0; r < 4; ++r) {
                    const int n = orow + i * 16 + r;
                    const int c = (ocol + j * 16) >> 1;
                    const float e = acc_e[i][j][r], o = acc_o[i][j][r];
                    dst[(size_t)n * 2048 + c]          = (unsigned short)f32_to_bf16_bits(e + o);
                    dst[(size_t)(4095 - n) * 2048 + c] = (unsigned short)f32_to_bf16_bits(e - o);
                }
    } else {
#pragma unroll
        for (int i = 0; i < 4; ++i)
#pragma unroll
            for (int j = 0; j < 4; ++j)
#pragma unroll
                for (int r = 0; r < 4; ++r) {
                    const int m = orow + i * 16 + r;
                    const int w = ocol + j * 16;
                    const float e = acc_e[i][j][r], o = acc_o[i][j][r];
                    out[(size_t)m * 4096 + w]          = e + o;
                    out[(size_t)(4095 - m) * 4096 + w] = e - o;
                }
    }
}

// ---------------------------------------------------------------------------
// Pipeline:
//   prep:   Ae,Ao (cosine tables) + Xe,Xo (deinterleaved bf16 x)
//   stage1: (Ae,Ao) x (Xe,Xo) -> butterfly -> Te,To (bf16, deinterleaved)
//   stage2: (Ae,Ao) x (Te,To) -> butterfly -> out (fp32)
// ws: Ae[0,8M) Ao[8,16M) Xe[16,32M) Xo[32,48M) Te[48,64M) To[64,80M)
// ---------------------------------------------------------------------------
extern "C" void kernel_launch(void* const* d_in, const int* in_sizes, int n_in,
                              void* d_out, int out_size, void* d_ws, size_t ws_size,
                              hipStream_t stream) {
    const float* x = (const float*)d_in[0];
    char* ws = (char*)d_ws;
    const size_t MB = 1024 * 1024;
    unsigned short* Ae = (unsigned short*)(ws);
    unsigned short* Ao = (unsigned short*)(ws + 8 * MB);
    unsigned short* Xe = (unsigned short*)(ws + 16 * MB);
    unsigned short* Xo = (unsigned short*)(ws + 32 * MB);
    unsigned short* Te = (unsigned short*)(ws + 48 * MB);
    unsigned short* To = (unsigned short*)(ws + 64 * MB);
    float* out = (float*)d_out;

    prep_kernel<<<12288, 256, 0, stream>>>(x, Ae, Ao, Xe, Xo);

    dim3 grid(32, 16);
    gemm_fused_kernel<1><<<grid, 256, 0, stream>>>(Ae, Ao, Xe, Xo, Te, To, nullptr);
    gemm_fused_kernel<2><<<grid, 256, 0, stream>>>(Ae, Ao, Te, To, nullptr, nullptr, out);
}